// Round 14
// baseline (105.016 us; speedup 1.0000x reference)
//
#include <hip/hip_runtime.h>
#include <hip/hip_bf16.h>

#define B 32
#define C 512
#define HW 3136            // 56*56 floats per plane
#define HW4 784            // fx4 per plane
#define TH 0.01f
#define NPG 32             // partial groups (blocks per batch)
#define CPB 16             // channels per block

typedef float fx4 __attribute__((ext_vector_type(4)));

// ---------------------------------------------------------------------------
// Kernel A: R9-exact (best known, 82.9 us). Quarter-plane per wave.
// Block = (b, pg) owns 16 channels; each wave owns fx4-cols [196w, 196w+196)
// of every channel. Per 2-channel group: cached loads, in-wave tree+shfl
// reduce -> plane sums, 16-float LDS exchange (parity, 1 barrier), alphas,
// FMA into per-wave acc (4 fx4). Waves store disjoint quarters of the
// partial plane (d_out plane pg). No fences/atomics (R10); launch_bounds
// (256,4) NOT (256,8) (R11 spill lesson).
// ---------------------------------------------------------------------------
__global__ __launch_bounds__(256, 4) void partial_kernel(const float* __restrict__ x,
                                                         float* __restrict__ out) {
    const int b  = blockIdx.y;
    const int pg = blockIdx.x;          // 0..NPG-1
    const int t  = threadIdx.x;
    const int l  = t & 63;
    const int wv = t >> 6;

    __shared__ float sums[2][2][4];     // [parity][channel][wave]

    const float* __restrict__ xb = x + (size_t)b * C * HW;
    const int qbase = wv * 196;         // this wave's fx4-col base

    fx4 acc0 = (fx4)0.f, acc1 = (fx4)0.f, acc2 = (fx4)0.f, acc3 = (fx4)0.f;

    #pragma unroll 2
    for (int g = 0; g < 8; ++g) {
        const int c0 = pg * CPB + 2 * g;
        const fx4* __restrict__ p0 = (const fx4*)(xb + (size_t)c0 * HW) + qbase + l;
        const fx4* __restrict__ p1 = (const fx4*)(xb + (size_t)(c0 + 1) * HW) + qbase + l;

        const fx4 a0 = p0[0], a1 = p0[64], a2 = p0[128];
        const fx4 b0 = p1[0], b1 = p1[64], b2 = p1[128];
        fx4 a3 = (fx4)0.f, b3 = (fx4)0.f;
        if (l < 4) { a3 = p0[192]; b3 = p1[192]; }

        float sa = (((a0.x + a0.y) + (a0.z + a0.w)) + ((a1.x + a1.y) + (a1.z + a1.w))) +
                   (((a2.x + a2.y) + (a2.z + a2.w)) + ((a3.x + a3.y) + (a3.z + a3.w)));
        float sb = (((b0.x + b0.y) + (b0.z + b0.w)) + ((b1.x + b1.y) + (b1.z + b1.w))) +
                   (((b2.x + b2.y) + (b2.z + b2.w)) + ((b3.x + b3.y) + (b3.z + b3.w)));
        #pragma unroll
        for (int off = 1; off < 64; off <<= 1) {
            sa += __shfl_xor(sa, off);
            sb += __shfl_xor(sb, off);
        }
        if (l == 0) {
            sums[g & 1][0][wv] = sa;
            sums[g & 1][1][wv] = sb;
        }
        __syncthreads();
        const float al0 = ((sums[g & 1][0][0] + sums[g & 1][0][1]) +
                           (sums[g & 1][0][2] + sums[g & 1][0][3])) * (1.0f / (float)HW);
        const float al1 = ((sums[g & 1][1][0] + sums[g & 1][1][1]) +
                           (sums[g & 1][1][2] + sums[g & 1][1][3])) * (1.0f / (float)HW);

        acc0 += a0 * al0 + b0 * al1;
        acc1 += a1 * al0 + b1 * al1;
        acc2 += a2 * al0 + b2 * al1;
        acc3 += a3 * al0 + b3 * al1;
    }

    // direct disjoint store of this wave's quarter (cached; B re-reads it)
    fx4* __restrict__ dst = (fx4*)(out + (size_t)b * C * HW + (size_t)pg * HW) + qbase + l;
    dst[0]   = acc0;
    dst[64]  = acc1;
    dst[128] = acc2;
    if (l < 4) dst[192] = acc3;
}

// ---------------------------------------------------------------------------
// Kernel B: R9 structure, ONE change: regular cached stores instead of
// nontemporal (isolating whether the NT store path caps write BW).
// Block = (b, tile of 16 fx4 cols). Partials live in d_out planes co=0..31,
// read before this block overwrites them (read->sync->write within block).
// ---------------------------------------------------------------------------
__global__ __launch_bounds__(256) void out_kernel(const float* __restrict__ w,
                                                  const float* __restrict__ scale_p,
                                                  const float* __restrict__ wf_p,
                                                  float* __restrict__ out) {
    const int b    = blockIdx.y;
    const int tile = blockIdx.x;               // 0..48
    const int t    = threadIdx.x;
    const int hw4  = t & 15;
    const int pg2  = t >> 4;                   // 0..15 -> partials 2*pg2, 2*pg2+1
    const int lane = t & 63;
    const int wid  = t >> 6;

    const fx4* __restrict__ P =
        (const fx4*)(out + (size_t)b * C * HW) + tile * 16 + hw4;
    fx4 s = P[(size_t)(2 * pg2) * HW4] + P[(size_t)(2 * pg2 + 1) * HW4];

    // reduce the 4 pg2-groups in this wave (lane deltas 16, 32)
    s.x += __shfl_xor(s.x, 16); s.y += __shfl_xor(s.y, 16);
    s.z += __shfl_xor(s.z, 16); s.w += __shfl_xor(s.w, 16);
    s.x += __shfl_xor(s.x, 32); s.y += __shfl_xor(s.y, 32);
    s.z += __shfl_xor(s.z, 32); s.w += __shfl_xor(s.w, 32);

    __shared__ fx4 red[4][16];
    if (lane < 16) red[wid][lane] = s;
    __syncthreads();

    __shared__ fx4 sal_sm[16];
    if (t < 16) {
        sal_sm[t] = ((red[0][t] + red[1][t]) + (red[2][t] + red[3][t])) *
                    (1.0f / (float)C);
    }
    __syncthreads();

    const float scale = scale_p[0];
    const float wf    = wf_p[0];
    const float out_zero = 1.0f - 0.5f * wf;   // fm == 0 path
    const fx4 s4 = sal_sm[hw4];

    fx4* __restrict__ ob = (fx4*)(out + (size_t)b * C * HW) + tile * 16 + hw4;
    const int c0 = pg2 * 32;                   // each group covers its 32 co's

    #pragma unroll 4
    for (int k = 0; k < 32; ++k) {
        const int co = c0 + k;
        const float wc = w[co];
        fx4 r;
        float fm;
        fm = s4.x * wc;
        r.x = (fm > TH) ? 1.0f - wf / (1.0f + __expf(-scale * fm)) : out_zero;
        fm = s4.y * wc;
        r.y = (fm > TH) ? 1.0f - wf / (1.0f + __expf(-scale * fm)) : out_zero;
        fm = s4.z * wc;
        r.z = (fm > TH) ? 1.0f - wf / (1.0f + __expf(-scale * fm)) : out_zero;
        fm = s4.w * wc;
        r.w = (fm > TH) ? 1.0f - wf / (1.0f + __expf(-scale * fm)) : out_zero;
        ob[(size_t)co * HW4] = r;              // regular cached store (was NT)
    }
}

extern "C" void kernel_launch(void* const* d_in, const int* in_sizes, int n_in,
                              void* d_out, int out_size, void* d_ws, size_t ws_size,
                              hipStream_t stream) {
    const float* x      = (const float*)d_in[0];
    const float* conv_w = (const float*)d_in[1];   // 512 floats
    const float* scale  = (const float*)d_in[2];
    const float* wf     = (const float*)d_in[3];
    float* out = (float*)d_out;

    dim3 gridA(NPG, B);                            // 32 x 32 = 1024 blocks
    partial_kernel<<<gridA, 256, 0, stream>>>(x, out);

    dim3 gridB(HW4 / 16, B);                       // 49 x 32 = 1568 blocks
    out_kernel<<<gridB, 256, 0, stream>>>(conv_w, scale, wf, out);
}